// Round 7
// baseline (310.093 us; speedup 1.0000x reference)
//
#include <hip/hip_runtime.h>
#include <hip/hip_bf16.h>

// Problem constants (match reference)
#define G_     64
#define NK     3
#define NB     64
#define IH     512
#define IW     512
#define NC     3
#define HG_    128
#define HL_    128
#define D_IN_    (NK * G_ * G_ * NC)   // 36864
#define D_SCALE  (G_ * G_ * NC)        // 12288
#define KCH      128                   // d per chunk (96 chunks per scale)
#define NCHUNK   (D_IN_ / KCH)         // 288
#define BSPLIT   4                     // batch groups of 16
#define NBLK     (NCHUNK * BSPLIT)     // 1152 blocks
#define PSTRIDE  (NB * HG_)            // 8192 floats per chunk-slice of P

// ---------------- Stage 1: pooling with fully-coalesced streaming reads ----
// One wave per task (k, gy, b): produce one pooled output row (64 cells x 3c).
// R6 lesson: per-thread strided gathers (24/48B stride) on cold HBM were the
// invariant never tested; here every global load instruction is 64 consecutive
// dwords (256B dense), staged through LDS, pooled from LDS with aligned reads.
template <int F>
__device__ __forceinline__ void pool_body(
    const float* __restrict__ x, const float* __restrict__ l,
    float* __restrict__ phi, int k, int gy, int b,
    float* __restrict__ lds_row, float* __restrict__ lds_out)
{
    const int lane = threadIdx.x & 63;
    const float lx = l[b * 2 + 0];
    const float ly = l[b * 2 + 1];
    // match reference: (0.5*(l+1.0)*512).astype(int32); single rounding at
    // (l+1.0f), *0.5 and *512 exact, trunc toward zero; cx,cy in [0,511]
    const int cx = (int)((0.5f * (lx + 1.0f)) * 512.0f);
    const int cy = (int)((0.5f * (ly + 1.0f)) * 512.0f);
    const int bx  = cx - 32 * F;              // window left pixel (may be <0)
    const int by0 = cy - 32 * F + gy * F;     // top row of this pooled row
    constexpr float inv = 1.0f / (float)(F * F);

    float a0 = 0.0f, a1 = 0.0f, a2 = 0.0f;
    const float* xb = x + (size_t)b * (IH * IW * NC);

#pragma unroll
    for (int dy = 0; dy < F; ++dy) {
        const int y = by0 + dy;
        const bool yok = (unsigned)y < (unsigned)IH;
        const int rowoff = y * (IW * NC) + bx * NC;   // float offset of window row
        // stage 192*F floats: lane reads consecutive dwords -> dense 256B/instr
#pragma unroll
        for (int ch = 0; ch < 3 * F; ++ch) {
            const int j  = ch * 64 + lane;            // float index within row span
            const int px = bx + j / 3;                // pixel this float belongs to
            const bool ok = yok && ((unsigned)px < (unsigned)IW);
            lds_row[ch * 64 + lane] = ok ? xb[rowoff + j] : 0.0f;  // masked load
        }
        // same-wave LDS RAW: hardware-ordered via lgkmcnt, no barrier needed
        if constexpr (F == 4) {
            const float4* p = (const float4*)(lds_row + lane * 12);  // 48B-aligned
            float4 t0 = p[0], t1 = p[1], t2 = p[2];
            a0 += t0.x + t0.w + t1.z + t2.y;   // c=0: m0,m3,m6,m9
            a1 += t0.y + t1.x + t1.w + t2.z;   // c=1: m1,m4,m7,m10
            a2 += t0.z + t1.y + t2.x + t2.w;   // c=2: m2,m5,m8,m11
        } else if constexpr (F == 2) {
            const float2* p = (const float2*)(lds_row + lane * 6);   // 24B-aligned
            float2 t0 = p[0], t1 = p[1], t2 = p[2];
            a0 += t0.x + t1.y;                 // m0,m3
            a1 += t0.y + t2.x;                 // m1,m4
            a2 += t1.x + t2.y;                 // m2,m5
        } else {
            a0 += lds_row[lane * 3 + 0];
            a1 += lds_row[lane * 3 + 1];
            a2 += lds_row[lane * 3 + 2];
        }
    }
    a0 *= inv; a1 *= inv; a2 *= inv;

    // stage 192 outputs in LDS, then 3 dense coalesced stores
    lds_out[lane * 3 + 0] = a0;
    lds_out[lane * 3 + 1] = a1;
    lds_out[lane * 3 + 2] = a2;
    float* op = phi + (size_t)b * D_IN_ + (size_t)((k * 64 + gy) * 64) * 3;
#pragma unroll
    for (int ch = 0; ch < 3; ++ch)
        op[ch * 64 + lane] = lds_out[ch * 64 + lane];
}

// 3072 blocks = 1024 per scale; block wave w handles batch (local&15)*4+w
__global__ __launch_bounds__(256) void pool(
    const float* __restrict__ x, const float* __restrict__ l,
    float* __restrict__ phi)
{
    __shared__ float lds[4][960];        // per-wave: 768 row-stage + 192 out
    const int wv    = threadIdx.x >> 6;
    const int k     = blockIdx.x >> 10;
    const int local = blockIdx.x & 1023;
    const int gy    = local >> 4;
    const int b     = (local & 15) * 4 + wv;
    float* lr = lds[wv];
    float* lo = lds[wv] + 768;
    if (k == 0)      pool_body<1>(x, l, phi, 0, gy, b, lr, lo);
    else if (k == 1) pool_body<2>(x, l, phi, 1, gy, b, lr, lo);
    else             pool_body<4>(x, l, phi, 2, gy, b, lr, lo);
}

// ---------------- Stage 2: split-K GEMV (R6 structure, phi from global) ----
__global__ __launch_bounds__(256) void gemm_p(
    const float* __restrict__ phi, const float* __restrict__ W1,
    float* __restrict__ P)
{
    __shared__ float phi_s[16][KCH];     // 8 KB
    const int tid = threadIdx.x;
    const int chunkGlobal = blockIdx.x >> 2;
    const int b0 = (blockIdx.x & 3) * 16;
    const int d0 = chunkGlobal * KCH;

    {   // coalesced tile load: 2 float4 per thread (32 lanes x 16B = 512B/row)
        const int r  = tid >> 5;
        const int c4 = (tid & 31) * 4;
        float4 v0 = *(const float4*)(phi + (size_t)(b0 + r) * D_IN_ + d0 + c4);
        float4 v1 = *(const float4*)(phi + (size_t)(b0 + r + 8) * D_IN_ + d0 + c4);
        *(float4*)&phi_s[r][c4]     = v0;
        *(float4*)&phi_s[r + 8][c4] = v1;
    }
    __syncthreads();

    const int h0 = (tid & 31) * 4;
    const int bl = (tid >> 5) * 2;
    float a0[4] = {0, 0, 0, 0}, a1[4] = {0, 0, 0, 0};
    const float* wp = W1 + (size_t)d0 * HG_ + h0;
    const float4* prow0 = (const float4*)phi_s[bl];
    const float4* prow1 = (const float4*)phi_s[bl + 1];

#pragma unroll 2
    for (int t = 0; t < KCH / 4; ++t) {
        float4 p0v = prow0[t];           // ds_read_b128
        float4 p1v = prow1[t];
#pragma unroll
        for (int u = 0; u < 4; ++u) {
            float4 wv = *(const float4*)(wp + (size_t)(4 * t + u) * HG_);
            float p0 = (&p0v.x)[u];
            float p1 = (&p1v.x)[u];
            a0[0] = fmaf(p0, wv.x, a0[0]);
            a0[1] = fmaf(p0, wv.y, a0[1]);
            a0[2] = fmaf(p0, wv.z, a0[2]);
            a0[3] = fmaf(p0, wv.w, a0[3]);
            a1[0] = fmaf(p1, wv.x, a1[0]);
            a1[1] = fmaf(p1, wv.y, a1[1]);
            a1[2] = fmaf(p1, wv.z, a1[2]);
            a1[3] = fmaf(p1, wv.w, a1[3]);
        }
    }
    float* pb = P + (size_t)chunkGlobal * PSTRIDE + (b0 + bl) * HG_ + h0;
    *(float4*)pb         = make_float4(a0[0], a0[1], a0[2], a0[3]);
    *(float4*)(pb + HG_) = make_float4(a1[0], a1[1], a1[2], a1[3]);
}

// ---------------- Stage 3: reduce partials + epilogue ---------------------
__global__ __launch_bounds__(256) void reduce_epilogue(
    const float* __restrict__ P,
    const float* __restrict__ l,
    const float* __restrict__ b1,
    const float* __restrict__ W2,
    const float* __restrict__ b2,
    float* __restrict__ out)
{
    __shared__ float red[HG_];
    const int b = blockIdx.x;
    const int t = threadIdx.x;
    const int h = t & (HG_ - 1);
    const int half = t >> 7;

    float s = 0.0f;
    const float* p = P + (size_t)(half * 144) * PSTRIDE + b * HG_ + h;
#pragma unroll 8
    for (int c = 0; c < 144; ++c)
        s += p[(size_t)c * PSTRIDE];

    if (half == 1) red[h] = s;
    __syncthreads();

    if (half == 0) {
        out[b * (HG_ + HL_) + h] = fmaxf(s + red[h] + b1[h], 0.0f);
    } else {
        float l0 = l[b * 2 + 0];
        float l1 = l[b * 2 + 1];
        float v = fmaf(l1, W2[HL_ + h], fmaf(l0, W2[h], b2[h]));
        out[b * (HG_ + HL_) + HG_ + h] = fmaxf(v, 0.0f);
    }
}

extern "C" void kernel_launch(void* const* d_in, const int* in_sizes, int n_in,
                              void* d_out, int out_size, void* d_ws, size_t ws_size,
                              hipStream_t stream) {
    const float* x  = (const float*)d_in[0];
    const float* l  = (const float*)d_in[1];
    const float* W1 = (const float*)d_in[2];
    const float* b1 = (const float*)d_in[3];
    const float* W2 = (const float*)d_in[4];
    const float* b2 = (const float*)d_in[5];
    float* out = (float*)d_out;
    float* P   = (float*)d_ws;                            // 9.4 MB partials
    float* phi = (float*)((char*)d_ws + (16 << 20));      // 9.4 MB pooled phi

    pool<<<3072, 256, 0, stream>>>(x, l, phi);
    gemm_p<<<NBLK, 256, 0, stream>>>(phi, W1, P);
    reduce_epilogue<<<NB, 256, 0, stream>>>(P, l, b1, W2, b2, out);
}